// Round 1
// baseline (5773.930 us; speedup 1.0000x reference)
//
#include <hip/hip_runtime.h>
#include <hip/hip_bf16.h>

typedef __hip_bfloat16 bf16;
using frag_ab = __attribute__((ext_vector_type(8))) short;  // 8 bf16 (4 VGPRs)
using f32x4  = __attribute__((ext_vector_type(4))) float;   // 4 fp32 acc

static constexpr int TSTEPS = 128;
static constexpr int BB = 512;   // batch
static constexpr int HH = 512;   // hidden
static constexpr int KK = 512;   // per-operand K
static constexpr int G4 = 2048;  // 4*H

// ---------------- conversion / init kernels ----------------

__global__ void k_f32_to_bf16_v4(const float4* __restrict__ src,
                                 ushort4* __restrict__ dst, int n4) {
  int i = blockIdx.x * blockDim.x + threadIdx.x;
  int stride = gridDim.x * blockDim.x;
  for (; i < n4; i += stride) {
    float4 v = src[i];
    ushort4 o;
    bf16 t0 = __float2bfloat16(v.x); o.x = *reinterpret_cast<unsigned short*>(&t0);
    bf16 t1 = __float2bfloat16(v.y); o.y = *reinterpret_cast<unsigned short*>(&t1);
    bf16 t2 = __float2bfloat16(v.z); o.z = *reinterpret_cast<unsigned short*>(&t2);
    bf16 t3 = __float2bfloat16(v.w); o.w = *reinterpret_cast<unsigned short*>(&t3);
    dst[i] = o;
  }
}

__global__ void k_bias(const float* __restrict__ bih0, const float* __restrict__ bhh0,
                       const float* __restrict__ bih1, const float* __restrict__ bhh1,
                       float* __restrict__ bsum0, float* __restrict__ bsum1) {
  int i = blockIdx.x * blockDim.x + threadIdx.x;
  if (i < G4) {
    bsum0[i] = bih0[i] + bhh0[i];
    bsum1[i] = bih1[i] + bhh1[i];
  }
}

// init running state: bf16 h buffer 0 (both layers), fp32 c (in d_out c_n region),
// fp32 h (in d_out h_n region)
__global__ void k_init(const float* __restrict__ h0, const float* __restrict__ c0,
                       bf16* __restrict__ hbuf0, float* __restrict__ c_state,
                       float* __restrict__ hn_out, int n) {
  int i = blockIdx.x * blockDim.x + threadIdx.x;
  int stride = gridDim.x * blockDim.x;
  for (; i < n; i += stride) {
    float hv = h0[i];
    hbuf0[i] = __float2bfloat16(hv);
    hn_out[i] = hv;
    c_state[i] = c0[i];
  }
}

// ---------------- fused LSTM cell kernel ----------------
// One workgroup = 32x32 (batch x hidden) output tile. 4 waves, wave w = gate w.
// gates = X @ W_ih^T + mask(Hprev) @ W_hh^T + bsum, then cell elementwise.
// gate order: 0=i, 1=f, 2=g(tanh), 3=o.
__global__ __launch_bounds__(256)
void k_cell(const bf16* __restrict__ X,      // (B,512) bf16, NOT reset-masked
            const bf16* __restrict__ Hprev,  // (B,512) bf16, reset-masked on load
            const bf16* __restrict__ W_ih,   // (2048,512) bf16 row-major
            const bf16* __restrict__ W_hh,   // (2048,512) bf16 row-major
            const float* __restrict__ bsum,  // (2048) b_ih + b_hh
            const int* __restrict__ reset,   // (B) this step's reset mask
            float* __restrict__ c_state,     // (B,H) fp32 running c (in d_out)
            float* __restrict__ h_f32,       // (B,H) fp32 running h (in d_out h_n)
            bf16* __restrict__ h_b16,        // (B,H) bf16 h for next step
            float* __restrict__ hidden)      // (B,H) hidden[t] or nullptr
{
  __shared__ float lds[4][32][33];

  const int tid  = threadIdx.x;
  const int wave = tid >> 6;        // gate index
  const int lane = tid & 63;
  const int r16  = lane & 15;
  const int kq   = lane >> 4;       // 0..3
  const int b0   = blockIdx.x * 32; // batch tile base
  const int h0   = blockIdx.y * 32; // hidden tile base

  const int rowA0 = b0 + r16;
  const int rowA1 = b0 + 16 + r16;
  const int rst0 = reset[rowA0];
  const int rst1 = reset[rowA1];

  f32x4 acc[2][2] = {};
  const frag_ab zf = {0, 0, 0, 0, 0, 0, 0, 0};

  // B-fragment row bases in W (row = gate*512 + output col)
  const bf16* wih_base = W_ih + (size_t)(wave * HH + h0) * KK;
  const bf16* whh_base = W_hh + (size_t)(wave * HH + h0) * KK;

  // ---- x part: K = 512 ----
  for (int kb = 0; kb < KK; kb += 32) {
    const int k = kb + kq * 8;
    frag_ab a0 = *reinterpret_cast<const frag_ab*>(X + (size_t)rowA0 * KK + k);
    frag_ab a1 = *reinterpret_cast<const frag_ab*>(X + (size_t)rowA1 * KK + k);
    frag_ab bf0 = *reinterpret_cast<const frag_ab*>(wih_base + (size_t)r16 * KK + k);
    frag_ab bf1 = *reinterpret_cast<const frag_ab*>(wih_base + (size_t)(16 + r16) * KK + k);
    acc[0][0] = __builtin_amdgcn_mfma_f32_16x16x32_bf16(a0, bf0, acc[0][0], 0, 0, 0);
    acc[0][1] = __builtin_amdgcn_mfma_f32_16x16x32_bf16(a0, bf1, acc[0][1], 0, 0, 0);
    acc[1][0] = __builtin_amdgcn_mfma_f32_16x16x32_bf16(a1, bf0, acc[1][0], 0, 0, 0);
    acc[1][1] = __builtin_amdgcn_mfma_f32_16x16x32_bf16(a1, bf1, acc[1][1], 0, 0, 0);
  }

  // ---- h part: K = 512, rows masked by reset ----
  for (int kb = 0; kb < KK; kb += 32) {
    const int k = kb + kq * 8;
    frag_ab a0 = rst0 ? zf : *reinterpret_cast<const frag_ab*>(Hprev + (size_t)rowA0 * KK + k);
    frag_ab a1 = rst1 ? zf : *reinterpret_cast<const frag_ab*>(Hprev + (size_t)rowA1 * KK + k);
    frag_ab bf0 = *reinterpret_cast<const frag_ab*>(whh_base + (size_t)r16 * KK + k);
    frag_ab bf1 = *reinterpret_cast<const frag_ab*>(whh_base + (size_t)(16 + r16) * KK + k);
    acc[0][0] = __builtin_amdgcn_mfma_f32_16x16x32_bf16(a0, bf0, acc[0][0], 0, 0, 0);
    acc[0][1] = __builtin_amdgcn_mfma_f32_16x16x32_bf16(a0, bf1, acc[0][1], 0, 0, 0);
    acc[1][0] = __builtin_amdgcn_mfma_f32_16x16x32_bf16(a1, bf0, acc[1][0], 0, 0, 0);
    acc[1][1] = __builtin_amdgcn_mfma_f32_16x16x32_bf16(a1, bf1, acc[1][1], 0, 0, 0);
  }

  // ---- bias + activation, park in LDS ----
  // C/D layout: col = lane&15, row = (lane>>4)*4 + reg
  #pragma unroll
  for (int mi = 0; mi < 2; ++mi) {
    #pragma unroll
    for (int ni = 0; ni < 2; ++ni) {
      #pragma unroll
      for (int j = 0; j < 4; ++j) {
        int row = mi * 16 + kq * 4 + j;
        int col = ni * 16 + r16;
        float v = acc[mi][ni][j] + bsum[wave * HH + h0 + col];
        v = (wave == 2) ? tanhf(v) : (1.0f / (1.0f + __expf(-v)));
        lds[wave][row][col] = v;
      }
    }
  }
  __syncthreads();

  // ---- cell elementwise: 1024 outputs, 256 threads ----
  #pragma unroll
  for (int q = 0; q < 4; ++q) {
    int idx = tid + q * 256;
    int r = idx >> 5, cc = idx & 31;
    int b = b0 + r, hh = h0 + cc;
    float iv = lds[0][r][cc];
    float fv = lds[1][r][cc];
    float gv = lds[2][r][cc];
    float ov = lds[3][r][cc];
    size_t off = (size_t)b * HH + hh;
    float cold = reset[b] ? 0.0f : c_state[off];
    float cnew = fv * cold + iv * gv;
    float hnew = ov * tanhf(cnew);
    c_state[off] = cnew;
    h_f32[off] = hnew;
    h_b16[off] = __float2bfloat16(hnew);
    if (hidden) hidden[off] = hnew;
  }
}

// ---------------- host ----------------

extern "C" void kernel_launch(void* const* d_in, const int* in_sizes, int n_in,
                              void* d_out, int out_size, void* d_ws, size_t ws_size,
                              hipStream_t stream) {
  (void)in_sizes; (void)n_in; (void)out_size; (void)ws_size;

  const float* latent = (const float*)d_in[0];
  const float* h0     = (const float*)d_in[1];
  const float* c0     = (const float*)d_in[2];
  const int*   reset  = (const int*)d_in[3];
  const float* W_ih0  = (const float*)d_in[4];
  const float* W_hh0  = (const float*)d_in[5];
  const float* b_ih0  = (const float*)d_in[6];
  const float* b_hh0  = (const float*)d_in[7];
  const float* W_ih1  = (const float*)d_in[8];
  const float* W_hh1  = (const float*)d_in[9];
  const float* b_ih1  = (const float*)d_in[10];
  const float* b_hh1  = (const float*)d_in[11];

  float* out    = (float*)d_out;
  float* hidden = out;                                   // (T,B,H)
  float* hn     = out + (size_t)TSTEPS * BB * HH;        // (L,B,H)
  float* cn     = hn + (size_t)2 * BB * HH;              // (L,B,H)

  // workspace layout
  char* ws = (char*)d_ws;
  bf16* latb  = (bf16*)ws;                               // T*B*512 bf16
  bf16* wih0b = latb + (size_t)TSTEPS * BB * KK;
  bf16* whh0b = wih0b + (size_t)G4 * KK;
  bf16* wih1b = whh0b + (size_t)G4 * KK;
  bf16* whh1b = wih1b + (size_t)G4 * KK;
  float* bsum0 = (float*)(whh1b + (size_t)G4 * KK);
  float* bsum1 = bsum0 + G4;
  bf16* hbuf   = (bf16*)(bsum1 + G4);                    // [2 bufs][2 layers][B*H]
  const size_t BUFSTRIDE = (size_t)2 * BB * HH;          // per double-buffer
  const size_t LSTRIDE   = (size_t)BB * HH;              // per layer

  // conversions (every call: stateless/deterministic)
  int n_lat4 = TSTEPS * BB * KK / 4;
  k_f32_to_bf16_v4<<<2048, 256, 0, stream>>>((const float4*)latent, (ushort4*)latb, n_lat4);
  int n_w4 = G4 * KK / 4;
  k_f32_to_bf16_v4<<<256, 256, 0, stream>>>((const float4*)W_ih0, (ushort4*)wih0b, n_w4);
  k_f32_to_bf16_v4<<<256, 256, 0, stream>>>((const float4*)W_hh0, (ushort4*)whh0b, n_w4);
  k_f32_to_bf16_v4<<<256, 256, 0, stream>>>((const float4*)W_ih1, (ushort4*)wih1b, n_w4);
  k_f32_to_bf16_v4<<<256, 256, 0, stream>>>((const float4*)W_hh1, (ushort4*)whh1b, n_w4);
  k_bias<<<(G4 + 255) / 256, 256, 0, stream>>>(b_ih0, b_hh0, b_ih1, b_hh1, bsum0, bsum1);
  k_init<<<512, 256, 0, stream>>>(h0, c0, hbuf /*buffer 0*/, cn, hn, 2 * BB * HH);

  dim3 grid(BB / 32, HH / 32);  // (16,16)
  dim3 blk(256);
  for (int t = 0; t < TSTEPS; ++t) {
    const bf16* Hp0 = hbuf + (size_t)(t & 1) * BUFSTRIDE;
    const bf16* Hp1 = Hp0 + LSTRIDE;
    bf16* Hn0 = hbuf + (size_t)((t + 1) & 1) * BUFSTRIDE;
    bf16* Hn1 = Hn0 + LSTRIDE;
    const int* rst = reset + (size_t)t * BB;

    // layer 0: x = latent[t]
    k_cell<<<grid, blk, 0, stream>>>(latb + (size_t)t * BB * KK, Hp0,
                                     wih0b, whh0b, bsum0, rst,
                                     cn, hn, Hn0, nullptr);
    // layer 1: x = h0n (just written, stream-ordered)
    k_cell<<<grid, blk, 0, stream>>>(Hn0, Hp1,
                                     wih1b, whh1b, bsum1, rst,
                                     cn + LSTRIDE, hn + LSTRIDE, Hn1,
                                     hidden + (size_t)t * BB * HH);
  }
}